// Round 2
// baseline (870.060 us; speedup 1.0000x reference)
//
#include <hip/hip_runtime.h>

// ============================================================================
// MolecularGraphNeuralNetwork — fused, one workgroup per molecule.
// ROUND 2 = ablation build: attention PV path switched from
// (bf16 S' -> LDS -> PV-MFMA) to (f32 S in accumulators -> __shfl broadcast
// -> VALU FMA against f32 hs3^T in LDS).  GEMMs (hs1/hs2/hs3, S) unchanged.
// ============================================================================

#define NB   1024
#define NN   256
#define DD   64
#define NLAY 3

typedef __attribute__((ext_vector_type(8))) short s16x8;
typedef __attribute__((ext_vector_type(4))) float f32x4;

static __device__ __forceinline__ short f2bf(float x) {
    union { float f; unsigned u; } v; v.f = x;
    unsigned r = v.u + 0x7FFFu + ((v.u >> 16) & 1u);   // RNE
    return (short)(r >> 16);
}

#define MFMA(a, bb, acc) __builtin_amdgcn_mfma_f32_16x16x32_bf16((a), (bb), (acc), 0, 0, 0)

// stage a C-layout [2][4][4] f32 register array into this wave's 32-row strip
// of hs2s as bf16 (wave-private rows -> no barrier needed around it)
#define STAGE_STRIP(arr)                                                      \
    do {                                                                      \
        _Pragma("unroll") for (int tr_ = 0; tr_ < 2; ++tr_)                   \
        _Pragma("unroll") for (int et_ = 0; et_ < 4; ++et_)                   \
        _Pragma("unroll") for (int r_ = 0; r_ < 4; ++r_)                      \
            hs2s[n0 + tr_*16 + g*4 + r_][et_*16 + c] = f2bf(arr[tr_][et_][r_]); \
    } while (0)

// read this wave's strip back as MFMA A-fragments [tr][kblock]
#define READ_AFRAG(dst)                                                       \
    do {                                                                      \
        _Pragma("unroll") for (int tr_ = 0; tr_ < 2; ++tr_)                   \
        _Pragma("unroll") for (int kb_ = 0; kb_ < 2; ++kb_)                   \
            dst[tr_][kb_] = *(const s16x8*)&hs2s[n0 + tr_*16 + c][kb_*32 + g*8]; \
    } while (0)

// adjacency loads in accumulator-fragment layout for chunk cc
#define LOADA(cc, am)                                                         \
    do {                                                                      \
        _Pragma("unroll") for (int tr_ = 0; tr_ < 2; ++tr_)                   \
        _Pragma("unroll") for (int mc_ = 0; mc_ < 2; ++mc_)                   \
        _Pragma("unroll") for (int r_ = 0; r_ < 4; ++r_)                      \
            am[tr_][mc_][r_] = adjB[(size_t)(n0 + tr_*16 + g*4 + r_)*NN + (cc)*32 + mc_*16 + c]; \
    } while (0)

__global__ __launch_bounds__(512, 2)
void mgnn_fused(const int* __restrict__ fpr, const float* __restrict__ adj,
                const float* __restrict__ wemb, const float* __restrict__ pemb,
                const float* __restrict__ egp, const float* __restrict__ ebp,
                const float* __restrict__ W1p, const float* __restrict__ b1p,
                const float* __restrict__ W2p, const float* __restrict__ b2p,
                const float* __restrict__ W3p, const float* __restrict__ b3p,
                const float* __restrict__ lngp, const float* __restrict__ lnbp,
                float* __restrict__ out)
{
    // LDS: 36,864 + 66,816 = 103,680 B (<= 160 KiB)
    __shared__ __align__(16) short hs2s[NN][72];     // bf16 staging (xs/hs1/hs2)
    __shared__ __align__(16) float hs3Tf[DD][261];   // hs3 transposed, f32, +5 pad

    const int b    = blockIdx.x;
    const int tid  = threadIdx.x;
    const int w    = tid >> 6;      // wave 0..7
    const int lane = tid & 63;
    const int g    = lane >> 4;     // lane group 0..3
    const int c    = lane & 15;     // lane-in-group 0..15
    const int n0   = w * 32;        // this wave's row strip

    const float* __restrict__ adjB = adj + (size_t)b * NN * NN;

    float lngv[4], lnbv[4], egv[4], ebv[4];
    #pragma unroll
    for (int dc = 0; dc < 4; ++dc) {
        lngv[dc] = lngp[dc*16 + c];
        lnbv[dc] = lnbp[dc*16 + c];
        egv[dc]  = egp[dc*16 + c];
        ebv[dc]  = ebp[dc*16 + c];
    }

    // ---------------- embedding + LayerNorm -> xsC (C-layout f32) ----------
    float xsC[2][4][4];   // [tr][dc][r] : row n0+tr*16+g*4+r, col dc*16+c
    #pragma unroll
    for (int tr = 0; tr < 2; ++tr) {
        #pragma unroll
        for (int r = 0; r < 4; ++r) {
            const int n = n0 + tr*16 + g*4 + r;
            const int f = fpr[b*NN + n];
            float vv[4], s1 = 0.f, s2 = 0.f;
            #pragma unroll
            for (int dc = 0; dc < 4; ++dc) {
                const int d = dc*16 + c;
                const float v = wemb[f*DD + d] + pemb[n*DD + d];
                vv[dc] = v; s1 += v; s2 += v*v;
            }
            #pragma unroll
            for (int off = 1; off < 16; off <<= 1) {
                s1 += __shfl_xor(s1, off);
                s2 += __shfl_xor(s2, off);
            }
            const float mu  = s1 * 0.015625f;
            const float var = s2 * 0.015625f - mu*mu;
            const float rs  = rsqrtf(var + 1e-6f);
            #pragma unroll
            for (int dc = 0; dc < 4; ++dc)
                xsC[tr][dc][r] = (vv[dc] - mu) * rs * egv[dc] + ebv[dc];
        }
    }

    // xs as bf16 A-fragments
    s16x8 xsf[2][2];
    STAGE_STRIP(xsC);
    __syncthreads();
    READ_AFRAG(xsf);

    float hsv[2][4][4];   // shared GEMM output buffer (registers)

    // GEMM: hsv = relu(xs @ W^T + bias), W is [e][d] row-major f32 in global
    auto gemmHs = [&](const float* __restrict__ Wm, const float* __restrict__ bm) {
        s16x8 wf[4][2];
        #pragma unroll
        for (int et = 0; et < 4; ++et) {
            const float* p = Wm + (et*16 + c)*DD + g*8;   // row e=et*16+c, d0=g*8
            #pragma unroll
            for (int kb = 0; kb < 2; ++kb) {
                s16x8 v;
                #pragma unroll
                for (int j = 0; j < 8; ++j) v[j] = f2bf(p[kb*32 + j]);
                wf[et][kb] = v;
            }
        }
        #pragma unroll
        for (int tr = 0; tr < 2; ++tr) {
            #pragma unroll
            for (int et = 0; et < 4; ++et) {
                f32x4 acc = {0.f, 0.f, 0.f, 0.f};
                acc = MFMA(xsf[tr][0], wf[et][0], acc);
                acc = MFMA(xsf[tr][1], wf[et][1], acc);
                const float bv = bm[et*16 + c];
                #pragma unroll
                for (int r = 0; r < 4; ++r)
                    hsv[tr][et][r] = fmaxf(acc[r] + bv, 0.f);
            }
        }
    };

    #pragma unroll 1
    for (int l = 0; l < NLAY; ++l) {
        // ---- hs1: GEMM -> stage -> read back as A-frags (wave-private strip)
        gemmHs(W1p + l*DD*DD, b1p + l*DD);
        STAGE_STRIP(hsv);
        __syncthreads();
        s16x8 h1f[2][2];
        READ_AFRAG(h1f);

        // ---- hs2 into LDS row-major (B-operand of S)
        gemmHs(W2p + l*DD*DD, b2p + l*DD);
        STAGE_STRIP(hsv);

        // ---- hs3 into LDS transposed [d][m], f32
        gemmHs(W3p + l*DD*DD, b3p + l*DD);
        #pragma unroll
        for (int tr = 0; tr < 2; ++tr)
            #pragma unroll
            for (int et = 0; et < 4; ++et)
                #pragma unroll
                for (int r = 0; r < 4; ++r)
                    hs3Tf[et*16 + c][n0 + tr*16 + g*4 + r] = hsv[tr][et][r];
        __syncthreads();   // hs2/hs3T now visible to all waves

        // ---- masked attention + PV over 8 chunks of 32 columns -----------
        float pv[2][4][4];
        #pragma unroll
        for (int tr = 0; tr < 2; ++tr)
            #pragma unroll
            for (int dc = 0; dc < 4; ++dc)
                #pragma unroll
                for (int r = 0; r < 4; ++r) pv[tr][dc][r] = 0.f;

        #pragma unroll 1
        for (int cc = 0; cc < 8; ++cc) {
            float am[2][2][4];
            LOADA(cc, am);

            // S = hs1 @ hs2^T (MFMA, f32 accum), masked in f32, kept in regs
            float sm[2][2][4];
            #pragma unroll
            for (int mc = 0; mc < 2; ++mc) {
                const s16x8 b0 = *(const s16x8*)&hs2s[cc*32 + mc*16 + c][g*8];
                const s16x8 b1 = *(const s16x8*)&hs2s[cc*32 + mc*16 + c][32 + g*8];
                #pragma unroll
                for (int tr = 0; tr < 2; ++tr) {
                    f32x4 s = {0.f, 0.f, 0.f, 0.f};
                    s = MFMA(h1f[tr][0], b0, s);
                    s = MFMA(h1f[tr][1], b1, s);
                    #pragma unroll
                    for (int r = 0; r < 4; ++r)
                        sm[tr][mc][r] = s[r] * am[tr][mc][r];
                }
            }

            // PV: pv[n][d] += sum_m S'[n][m] * hs3[m][d]  (shfl broadcast + FMA)
            #pragma unroll
            for (int mc = 0; mc < 2; ++mc) {
                #pragma unroll 4
                for (int m16 = 0; m16 < 16; ++m16) {
                    const int src = (lane & 48) | m16;   // same g-group, c=m16
                    float sb[2][4];
                    #pragma unroll
                    for (int tr = 0; tr < 2; ++tr)
                        #pragma unroll
                        for (int r = 0; r < 4; ++r)
                            sb[tr][r] = __shfl(sm[tr][mc][r], src);
                    float h3v[4];
                    const int m = cc*32 + mc*16 + m16;
                    #pragma unroll
                    for (int dc = 0; dc < 4; ++dc)
                        h3v[dc] = hs3Tf[dc*16 + c][m];
                    #pragma unroll
                    for (int tr = 0; tr < 2; ++tr)
                        #pragma unroll
                        for (int dc = 0; dc < 4; ++dc)
                            #pragma unroll
                            for (int r = 0; r < 4; ++r)
                                pv[tr][dc][r] = fmaf(sb[tr][r], h3v[dc], pv[tr][dc][r]);
                }
            }
        }

        // ---- LayerNorm(pv) + residual into xsC ----------------------------
        #pragma unroll
        for (int tr = 0; tr < 2; ++tr) {
            #pragma unroll
            for (int r = 0; r < 4; ++r) {
                float s1 = 0.f, s2 = 0.f;
                #pragma unroll
                for (int dc = 0; dc < 4; ++dc) {
                    const float v = pv[tr][dc][r];
                    s1 += v; s2 += v*v;
                }
                #pragma unroll
                for (int off = 1; off < 16; off <<= 1) {
                    s1 += __shfl_xor(s1, off);
                    s2 += __shfl_xor(s2, off);
                }
                const float mu  = s1 * 0.015625f;
                const float var = s2 * 0.015625f - mu*mu;
                const float rs  = rsqrtf(var + 1e-6f);
                #pragma unroll
                for (int dc = 0; dc < 4; ++dc)
                    xsC[tr][dc][r] += (pv[tr][dc][r] - mu) * rs * lngv[dc] + lnbv[dc];
            }
        }

        // ---- re-stage xs for next layer -----------------------------------
        if (l < NLAY - 1) {
            __syncthreads();          // all waves done reading hs2s/hs3Tf
            STAGE_STRIP(xsC);
            __syncthreads();
            READ_AFRAG(xsf);
        }
    }

    // ---------------- final output (f32, coalesced 64B per 16 lanes) -------
    const size_t ob = (size_t)b * NN * DD;
    #pragma unroll
    for (int tr = 0; tr < 2; ++tr) {
        #pragma unroll
        for (int r = 0; r < 4; ++r) {
            const int n = n0 + tr*16 + g*4 + r;
            #pragma unroll
            for (int dc = 0; dc < 4; ++dc)
                out[ob + (size_t)n*DD + dc*16 + c] = xsC[tr][dc][r];
        }
    }
}

extern "C" void kernel_launch(void* const* d_in, const int* in_sizes, int n_in,
                              void* d_out, int out_size, void* d_ws, size_t ws_size,
                              hipStream_t stream) {
    const int*   fpr  = (const int*)  d_in[0];
    const float* adj  = (const float*)d_in[1];
    // d_in[2] = molecular_sizes — unused by the reference computation
    const float* wemb = (const float*)d_in[3];
    const float* pemb = (const float*)d_in[4];
    const float* eg   = (const float*)d_in[5];
    const float* eb   = (const float*)d_in[6];
    const float* W1   = (const float*)d_in[7];
    const float* b1   = (const float*)d_in[8];
    const float* W2   = (const float*)d_in[9];
    const float* b2   = (const float*)d_in[10];
    const float* W3   = (const float*)d_in[11];
    const float* b3   = (const float*)d_in[12];
    const float* lng  = (const float*)d_in[13];
    const float* lnb  = (const float*)d_in[14];

    mgnn_fused<<<dim3(NB), dim3(512), 0, stream>>>(
        fpr, adj, wemb, pemb, eg, eb, W1, b1, W2, b2, W3, b3, lng, lnb,
        (float*)d_out);
}

// Round 4
// 312.851 us; speedup vs baseline: 2.7811x; 2.7811x over previous
//
#include <hip/hip_runtime.h>

// ============================================================================
// MolecularGraphNeuralNetwork — fused, one workgroup per molecule.
// ROUND 4: PV via MFMA with NO LDS round-trip for S'.
//   - S^T computed by operand-swapped MFMA (hs2-frag in A-slot, hs1 in B-slot)
//   - masked with transposed adjacency reads (adj is symmetric)
//   - PV B-operand built in registers from S^T accumulators (2 shfl + select)
//   - PV output is transposed (lane holds row n=c, cols d=4g+r) -> xs kept in
//     that layout end-to-end (embedding, LN, residual, out-write flipped).
// Chunk loop contains ZERO LDS writes -> no ordering hazards.
// ============================================================================

#define NB   1024
#define NN   256
#define DD   64
#define NLAY 3

typedef __attribute__((ext_vector_type(8))) short s16x8;
typedef __attribute__((ext_vector_type(4))) short s16x4;
typedef __attribute__((ext_vector_type(4))) float f32x4;

static __device__ __forceinline__ short f2bf(float x) {
    union { float f; unsigned u; } v; v.f = x;
    unsigned r = v.u + 0x7FFFu + ((v.u >> 16) & 1u);   // RNE
    return (short)(r >> 16);
}

#define MFMA(a, bb, acc) __builtin_amdgcn_mfma_f32_16x16x32_bf16((a), (bb), (acc), 0, 0, 0)

// stage gemm output hsv (acc layout: row 4g+r, col 16et+c) into wave strip
#define STAGE_STRIP(arr)                                                      \
    do {                                                                      \
        _Pragma("unroll") for (int tr_ = 0; tr_ < 2; ++tr_)                   \
        _Pragma("unroll") for (int et_ = 0; et_ < 4; ++et_)                   \
        _Pragma("unroll") for (int r_ = 0; r_ < 4; ++r_)                      \
            hs2s[n0 + tr_*16 + g*4 + r_][et_*16 + c] = f2bf(arr[tr_][et_][r_]); \
    } while (0)

// read this wave's strip back as MFMA A/B fragments [tr][kblock]
#define READ_AFRAG(dst)                                                       \
    do {                                                                      \
        _Pragma("unroll") for (int tr_ = 0; tr_ < 2; ++tr_)                   \
        _Pragma("unroll") for (int kb_ = 0; kb_ < 2; ++kb_)                   \
            dst[tr_][kb_] = *(const s16x8*)&hs2s[n0 + tr_*16 + c][kb_*32 + g*8]; \
    } while (0)

__global__ __launch_bounds__(512, 2)
void mgnn_fused(const int* __restrict__ fpr, const float* __restrict__ adj,
                const float* __restrict__ wemb, const float* __restrict__ pemb,
                const float* __restrict__ egp, const float* __restrict__ ebp,
                const float* __restrict__ W1p, const float* __restrict__ b1p,
                const float* __restrict__ W2p, const float* __restrict__ b2p,
                const float* __restrict__ W3p, const float* __restrict__ b3p,
                const float* __restrict__ lngp, const float* __restrict__ lnbp,
                float* __restrict__ out)
{
    // LDS: 36,864 + 33,792 = 70,656 B
    __shared__ __align__(16) short hs2s[NN][72];    // bf16 staging (xs/hs1/hs2)
    __shared__ __align__(16) short hs3Ts[DD][264];  // hs3^T bf16 [d][m], +8 pad

    const int b    = blockIdx.x;
    const int tid  = threadIdx.x;
    const int w    = tid >> 6;      // wave 0..7
    const int lane = tid & 63;
    const int g    = lane >> 4;     // lane group 0..3
    const int c    = lane & 15;     // lane-in-group 0..15
    const int n0   = w * 32;        // this wave's row strip

    const float* __restrict__ adjB = adj + (size_t)b * NN * NN;

    // ---- embedding + LN, TRANSPOSED layout:
    //      lane (g,c), tile tr holds row n = n0+16tr+c, cols d = 16dc+4g+r
    f32x4 xsC[2][4];
    #pragma unroll
    for (int tr = 0; tr < 2; ++tr) {
        const int n = n0 + tr*16 + c;
        const int f = fpr[b*NN + n];
        f32x4 v[4];
        float s1 = 0.f, s2 = 0.f;
        #pragma unroll
        for (int dc = 0; dc < 4; ++dc) {
            const f32x4 wv = *(const f32x4*)&wemb[f*DD + dc*16 + g*4];
            const f32x4 pe = *(const f32x4*)&pemb[n*DD + dc*16 + g*4];
            f32x4 t;
            #pragma unroll
            for (int r = 0; r < 4; ++r) {
                t[r] = wv[r] + pe[r]; s1 += t[r]; s2 += t[r]*t[r];
            }
            v[dc] = t;
        }
        s1 += __shfl_xor(s1, 16); s2 += __shfl_xor(s2, 16);
        s1 += __shfl_xor(s1, 32); s2 += __shfl_xor(s2, 32);
        const float mu  = s1 * 0.015625f;
        const float var = s2 * 0.015625f - mu*mu;
        const float rs  = rsqrtf(var + 1e-6f);
        #pragma unroll
        for (int dc = 0; dc < 4; ++dc) {
            const f32x4 eg = *(const f32x4*)&egp[dc*16 + g*4];
            const f32x4 eb = *(const f32x4*)&ebp[dc*16 + g*4];
            #pragma unroll
            for (int r = 0; r < 4; ++r)
                xsC[tr][dc][r] = (v[dc][r] - mu) * rs * eg[r] + eb[r];
        }
    }

    // stage xs (transposed regs -> row-major LDS strip): vector s16x4 stores
    auto stageXS = [&]() {
        #pragma unroll
        for (int tr = 0; tr < 2; ++tr)
            #pragma unroll
            for (int dc = 0; dc < 4; ++dc) {
                s16x4 pk;
                #pragma unroll
                for (int r = 0; r < 4; ++r) pk[r] = f2bf(xsC[tr][dc][r]);
                *(s16x4*)&hs2s[n0 + tr*16 + c][dc*16 + g*4] = pk;
            }
    };

    s16x8 xsf[2][2];
    stageXS();
    __syncthreads();
    READ_AFRAG(xsf);

    float hsv[2][4][4];   // gemm output, acc layout [tr][et][r]

    // hsv = relu(xs @ W^T + bias); W is [e][d] row-major f32
    auto gemmHs = [&](const float* __restrict__ Wm, const float* __restrict__ bm) {
        s16x8 wf[4][2];
        #pragma unroll
        for (int et = 0; et < 4; ++et) {
            const float* p = Wm + (et*16 + c)*DD + g*8;
            #pragma unroll
            for (int kb = 0; kb < 2; ++kb) {
                s16x8 v;
                #pragma unroll
                for (int j = 0; j < 8; ++j) v[j] = f2bf(p[kb*32 + j]);
                wf[et][kb] = v;
            }
        }
        #pragma unroll
        for (int tr = 0; tr < 2; ++tr) {
            #pragma unroll
            for (int et = 0; et < 4; ++et) {
                f32x4 acc = {0.f, 0.f, 0.f, 0.f};
                acc = MFMA(xsf[tr][0], wf[et][0], acc);
                acc = MFMA(xsf[tr][1], wf[et][1], acc);
                const float bv = bm[et*16 + c];
                #pragma unroll
                for (int r = 0; r < 4; ++r)
                    hsv[tr][et][r] = fmaxf(acc[r] + bv, 0.f);
            }
        }
    };

    #pragma unroll 1
    for (int l = 0; l < NLAY; ++l) {
        // ---- hs1 -> strip -> A/B-frags
        gemmHs(W1p + l*DD*DD, b1p + l*DD);
        STAGE_STRIP(hsv);
        __syncthreads();
        s16x8 h1f[2][2];
        READ_AFRAG(h1f);

        // ---- hs2 -> strip (row-major, read by all waves in chunk loop)
        gemmHs(W2p + l*DD*DD, b2p + l*DD);
        STAGE_STRIP(hsv);

        // ---- hs3 -> LDS transposed [d][m], bf16
        gemmHs(W3p + l*DD*DD, b3p + l*DD);
        #pragma unroll
        for (int tr = 0; tr < 2; ++tr) {
            #pragma unroll
            for (int et = 0; et < 4; ++et) {
                s16x4 pk;
                #pragma unroll
                for (int r = 0; r < 4; ++r) pk[r] = f2bf(hsv[tr][et][r]);
                *(s16x4*)&hs3Ts[et*16 + c][n0 + tr*16 + g*4] = pk;
            }
        }
        __syncthreads();   // hs2 strips + hs3T visible to all waves

        // ---- masked attention + PV, 8 chunks of 32 m-columns --------------
        // pv transposed: lane (g,c) tile (tr,dc): PV[n=n0+16tr+c][d=16dc+4g+r]
        f32x4 pv[2][4];
        {
            const f32x4 z4 = {0.f, 0.f, 0.f, 0.f};
            #pragma unroll
            for (int tr = 0; tr < 2; ++tr)
                #pragma unroll
                for (int dc = 0; dc < 4; ++dc) pv[tr][dc] = z4;
        }

        #pragma unroll 1
        for (int cc = 0; cc < 8; ++cc) {
            // transposed adjacency (adj symmetric): am[tr][mc][r] = adj[m][n]
            float amT[2][2][4];
            #pragma unroll
            for (int tr = 0; tr < 2; ++tr)
                #pragma unroll
                for (int mc = 0; mc < 2; ++mc)
                    #pragma unroll
                    for (int r = 0; r < 4; ++r)
                        amT[tr][mc][r] =
                            adjB[(size_t)(cc*32 + mc*16 + g*4 + r)*NN + n0 + tr*16 + c];

            // hs2 chunk-row fragments (A-slot of S^T)
            s16x8 a2[2][2];
            #pragma unroll
            for (int mc = 0; mc < 2; ++mc)
                #pragma unroll
                for (int kb = 0; kb < 2; ++kb)
                    a2[mc][kb] = *(const s16x8*)&hs2s[cc*32 + mc*16 + c][kb*32 + g*8];

            // hs3^T fragments (A-slot of PV)
            s16x8 h3f[4];
            #pragma unroll
            for (int dc = 0; dc < 4; ++dc)
                h3f[dc] = *(const s16x8*)&hs3Ts[dc*16 + c][cc*32 + g*8];

            // S^T tiles: reg r of lane (g,c) = S^T[m=16mc+4g+r][n=16tr+c], masked
            float smv[2][2][4];
            #pragma unroll
            for (int tr = 0; tr < 2; ++tr) {
                #pragma unroll
                for (int mc = 0; mc < 2; ++mc) {
                    f32x4 st = {0.f, 0.f, 0.f, 0.f};
                    st = MFMA(a2[mc][0], h1f[tr][0], st);
                    st = MFMA(a2[mc][1], h1f[tr][1], st);
                    #pragma unroll
                    for (int r = 0; r < 4; ++r)
                        smv[tr][mc][r] = st[r] * amT[tr][mc][r];
                }
            }

            // build PV B-operand in registers + PV MFMAs
            // elem j of lane (g,c) = S'^T[m=8g+j][n-col c]
            //   = reg (j&3), tile (g>>1), of lane (2*(g&1)+(j>>2))*16 + c
            #pragma unroll
            for (int tr = 0; tr < 2; ++tr) {
                s16x8 pb;
                #pragma unroll
                for (int j = 0; j < 8; ++j) {
                    const int srcl = ((2*(g & 1) + (j >> 2)) << 4) | c;
                    const float v0 = __shfl(smv[tr][0][j & 3], srcl);
                    const float v1 = __shfl(smv[tr][1][j & 3], srcl);
                    pb[j] = f2bf((g & 2) ? v1 : v0);
                }
                #pragma unroll
                for (int dc = 0; dc < 4; ++dc)
                    pv[tr][dc] = MFMA(h3f[dc], pb, pv[tr][dc]);
            }
        }

        // ---- LayerNorm(pv) + residual (transposed layout) ------------------
        #pragma unroll
        for (int tr = 0; tr < 2; ++tr) {
            float s1 = 0.f, s2 = 0.f;
            #pragma unroll
            for (int dc = 0; dc < 4; ++dc)
                #pragma unroll
                for (int r = 0; r < 4; ++r) {
                    const float x = pv[tr][dc][r];
                    s1 += x; s2 += x*x;
                }
            s1 += __shfl_xor(s1, 16); s2 += __shfl_xor(s2, 16);
            s1 += __shfl_xor(s1, 32); s2 += __shfl_xor(s2, 32);
            const float mu  = s1 * 0.015625f;
            const float var = s2 * 0.015625f - mu*mu;
            const float rs  = rsqrtf(var + 1e-6f);
            #pragma unroll
            for (int dc = 0; dc < 4; ++dc) {
                const f32x4 lg = *(const f32x4*)&lngp[dc*16 + g*4];
                const f32x4 lb = *(const f32x4*)&lnbp[dc*16 + g*4];
                #pragma unroll
                for (int r = 0; r < 4; ++r)
                    xsC[tr][dc][r] += (pv[tr][dc][r] - mu) * rs * lg[r] + lb[r];
            }
        }

        // ---- re-stage xs for next layer ------------------------------------
        if (l < NLAY - 1) {
            __syncthreads();          // all waves done reading hs2s/hs3Ts
            stageXS();
            __syncthreads();
            READ_AFRAG(xsf);
        }
    }

    // ---------------- final output: float4 per (tr,dc) ----------------------
    const size_t ob = (size_t)b * NN * DD;
    #pragma unroll
    for (int tr = 0; tr < 2; ++tr) {
        const int n = n0 + tr*16 + c;
        #pragma unroll
        for (int dc = 0; dc < 4; ++dc)
            *(f32x4*)&out[ob + (size_t)n*DD + dc*16 + g*4] = xsC[tr][dc];
    }
}

extern "C" void kernel_launch(void* const* d_in, const int* in_sizes, int n_in,
                              void* d_out, int out_size, void* d_ws, size_t ws_size,
                              hipStream_t stream) {
    const int*   fpr  = (const int*)  d_in[0];
    const float* adj  = (const float*)d_in[1];
    // d_in[2] = molecular_sizes — unused by the reference computation
    const float* wemb = (const float*)d_in[3];
    const float* pemb = (const float*)d_in[4];
    const float* eg   = (const float*)d_in[5];
    const float* eb   = (const float*)d_in[6];
    const float* W1   = (const float*)d_in[7];
    const float* b1   = (const float*)d_in[8];
    const float* W2   = (const float*)d_in[9];
    const float* b2   = (const float*)d_in[10];
    const float* W3   = (const float*)d_in[11];
    const float* b3   = (const float*)d_in[12];
    const float* lng  = (const float*)d_in[13];
    const float* lnb  = (const float*)d_in[14];

    mgnn_fused<<<dim3(NB), dim3(512), 0, stream>>>(
        fpr, adj, wemb, pemb, eg, eb, W1, b1, W2, b2, W3, b3, lng, lnb,
        (float*)d_out);
}